// Round 5
// baseline (229.190 us; speedup 1.0000x reference)
//
#include <hip/hip_runtime.h>
#include <math.h>

#define SL 2048   // sequence length L
#define NB 32     // batch
#define NH 128    // feature dim H
#define NP 256    // state dim P (complex)
#define NP2 512   // interleaved real/imag columns

typedef short bf16x8 __attribute__((ext_vector_type(8)));
typedef float f32x4  __attribute__((ext_vector_type(4)));

static __device__ __forceinline__ unsigned short f2bf(float x) {
    unsigned u = __float_as_uint(x);
    return (unsigned short)((u + 0x7fffu + ((u >> 16) & 1u)) >> 16);  // RNE
}
static __device__ __forceinline__ float bf2f(unsigned short h) {
    return __uint_as_float(((unsigned)h) << 16);
}
static __device__ __forceinline__ void discretize(
    const float* __restrict__ logLr, const float* __restrict__ Lim,
    const float* __restrict__ logDt, int p, float& wr, float& wi)
{
    const float Lr = expf(logLr[p]);
    const float dt = expf(logDt[p]);
    const float ew = expf(-Lr * dt);
    const float ang = Lim[p] * dt;
    wr = ew * cosf(ang); wi = ew * sinf(ang);
}

// ---------------------------------------------------------------------------
// k0: pack BhatF, fragment-major f_p*B_tilde: BhatF[kk=0..3][p'=0..511][32],
// so a gA wave's af load (lane=(q,c)) is one contiguous coalesced 1 KB.
// Also ChatF[kk=0..15][h=0..127][32] = fragment-major [Cr,-Ci].
// ---------------------------------------------------------------------------
__global__ __launch_bounds__(256) void k0(
    const float* __restrict__ logLr, const float* __restrict__ Lim,
    const float* __restrict__ logDt,
    const float* __restrict__ Br, const float* __restrict__ Bi,
    const float* __restrict__ Cr, const float* __restrict__ Ci,
    unsigned short* __restrict__ BhatF, unsigned short* __restrict__ ChatF)
{
    const int tid = blockIdx.x * 256 + threadIdx.x;  // 32768 = P*H
    const int p = tid >> 7, h = tid & 127;
    float wr, wi; discretize(logLr, Lim, logDt, p, wr, wi);
    const float Lr = expf(logLr[p]), li = Lim[p];
    const float nr = wr - 1.0f, ni = wi;
    const float den = Lr * Lr + li * li;
    const float fr = (-nr * Lr + ni * li) / den;
    const float fi = (-ni * Lr - nr * li) / den;
    const float br = Br[p * NH + h], bi = Bi[p * NH + h];
    // BhatF[(h>>5)<<14 | p'<<5 | (h&31)]
    BhatF[((size_t)(h >> 5) << 14) + ((2 * p)     << 5) + (h & 31)] = f2bf(fr * br - fi * bi);
    BhatF[((size_t)(h >> 5) << 14) + ((2 * p + 1) << 5) + (h & 31)] = f2bf(fr * bi + fi * br);
    const int col0 = 2 * p, col1 = 2 * p + 1;
    ChatF[((size_t)(col0 >> 5) << 12) + (h << 5) + (col0 & 31)] = f2bf(Cr[h * NP + p]);
    ChatF[((size_t)(col1 >> 5) << 12) + (h << 5) + (col1 & 31)] = f2bf(-Ci[h * NP + p]);
}

// ---------------------------------------------------------------------------
// gA: GEMM1 + bu store + 64-l carries. CHANGES this round:
//  - A-fragments no longer persistent in VGPRs: loaded per tile from BhatF
//    (L2-resident 128 KB, coalesced 1 KB/fragment) -> frees 128 VGPRs.
//  - us/xs share one LDS union (32.9 KB, disjoint live ranges, extra barrier).
//  => launch_bounds(256,4): 4 blocks/CU (was 2). Scan math unchanged.
// ---------------------------------------------------------------------------
__global__ __launch_bounds__(256, 4) void gA(
    const float* __restrict__ u, const unsigned short* __restrict__ BhatF,
    const float* __restrict__ logLr, const float* __restrict__ Lim,
    const float* __restrict__ logDt,
    unsigned short* __restrict__ bu, float2* __restrict__ part)
{
    __shared__ char smem[32 * 257 * 4];      // union: us (8704 B) / xs (32896 B)
    unsigned short (*us)[136] = (unsigned short(*)[136])smem;   // u tile bf16 [l][h], pad 8
    unsigned* xs = (unsigned*)smem;          // out tile [l][complex p], pitch 257

    const int seg = blockIdx.x;              // 0..15
    const int b   = blockIdx.y;
    const int tid = threadIdx.x;
    const int wave = tid >> 6, lane = tid & 63;
    const int q = lane >> 4, c = lane & 15;
    const int pbase = wave * 128;

    // scan constants for this thread's p = tid
    float wr, wi; discretize(logLr, Lim, logDt, tid, wr, wi);
    float W32r = wr, W32i = wi;
    #pragma unroll
    for (int t = 0; t < 5; ++t) { const float r = W32r * W32r - W32i * W32i;
                                  W32i = 2.f * W32r * W32i; W32r = r; }

    float2 pa = make_float2(0.f, 0.f);

    for (int t = 0; t < 4; ++t) {
        const int l0 = seg * 128 + t * 32;
        __syncthreads();   // prev scan xs reads done
        {   // stage u tile (32 l x 128 h) fp32 -> bf16 LDS
            const int lrow = tid >> 3;
            const int hcol = (tid & 7) * 16;
            const float* up = u + (size_t)(l0 + lrow) * (NB * NH) + b * NH + hcol;
            float4 a = *(const float4*)(up + 0);
            float4 d = *(const float4*)(up + 4);
            float4 e = *(const float4*)(up + 8);
            float4 g = *(const float4*)(up + 12);
            uint4 w0, w1;
            w0.x = (unsigned)f2bf(a.x) | ((unsigned)f2bf(a.y) << 16);
            w0.y = (unsigned)f2bf(a.z) | ((unsigned)f2bf(a.w) << 16);
            w0.z = (unsigned)f2bf(d.x) | ((unsigned)f2bf(d.y) << 16);
            w0.w = (unsigned)f2bf(d.z) | ((unsigned)f2bf(d.w) << 16);
            w1.x = (unsigned)f2bf(e.x) | ((unsigned)f2bf(e.y) << 16);
            w1.y = (unsigned)f2bf(e.z) | ((unsigned)f2bf(e.w) << 16);
            w1.z = (unsigned)f2bf(g.x) | ((unsigned)f2bf(g.y) << 16);
            w1.w = (unsigned)f2bf(g.z) | ((unsigned)f2bf(g.w) << 16);
            *(uint4*)&us[lrow][hcol + 0] = w0;
            *(uint4*)&us[lrow][hcol + 8] = w1;
        }
        __syncthreads();   // us ready

        f32x4 acc[8][2];
        #pragma unroll
        for (int mt = 0; mt < 8; ++mt)
            #pragma unroll
            for (int nt = 0; nt < 2; ++nt) acc[mt][nt] = (f32x4){0.f, 0.f, 0.f, 0.f};

        #pragma unroll
        for (int kk = 0; kk < 4; ++kk) {
            bf16x8 af[8];
            #pragma unroll
            for (int mt = 0; mt < 8; ++mt)
                af[mt] = *(const bf16x8*)(BhatF + ((size_t)kk << 14)
                                          + ((pbase + 16 * mt + c) << 5) + 8 * q);
            bf16x8 bfr[2];
            #pragma unroll
            for (int nt = 0; nt < 2; ++nt)
                bfr[nt] = *(const bf16x8*)&us[16 * nt + c][kk * 32 + 8 * q];
            #pragma unroll
            for (int mt = 0; mt < 8; ++mt)
                #pragma unroll
                for (int nt = 0; nt < 2; ++nt)
                    acc[mt][nt] = __builtin_amdgcn_mfma_f32_16x16x32_bf16(
                        af[mt], bfr[nt], acc[mt][nt], 0, 0, 0);
        }
        __syncthreads();   // us reads done before xs overwrites the union

        // store bu + stash xs
        #pragma unroll
        for (int mt = 0; mt < 8; ++mt)
            #pragma unroll
            for (int nt = 0; nt < 2; ++nt) {
                const int rw = 16 * nt + c;               // local l row
                const int pp = pbase + 16 * mt + 4 * q;   // p' base
                ushort4 st;
                st.x = f2bf(acc[mt][nt][0]); st.y = f2bf(acc[mt][nt][1]);
                st.z = f2bf(acc[mt][nt][2]); st.w = f2bf(acc[mt][nt][3]);
                *(ushort4*)(bu + ((size_t)(b * SL + l0 + rw)) * NP2 + pp) = st;
                const int col = (pp >> 1);                // complex index
                xs[rw * 257 + col]     = (unsigned)st.x | ((unsigned)st.y << 16);
                xs[rw * 257 + col + 1] = (unsigned)st.z | ((unsigned)st.w << 16);
            }
        __syncthreads();   // xs ready

        // carry-only scan of column p = tid over 32 rows
        {
            float sr = 0.f, si = 0.f;
            unsigned va[8], vb[8];
            #pragma unroll
            for (int j = 0; j < 8; ++j) va[j] = xs[j * 257 + tid];
            #pragma unroll
            for (int k8 = 0; k8 < 4; ++k8) {
                if (k8 < 3) {
                    #pragma unroll
                    for (int j = 0; j < 8; ++j) vb[j] = xs[((k8 + 1) * 8 + j) * 257 + tid];
                }
                #pragma unroll
                for (int j = 0; j < 8; ++j) {
                    const float xr = bf2f((unsigned short)(va[j] & 0xffffu));
                    const float xi = bf2f((unsigned short)(va[j] >> 16));
                    const float tr = wr * sr - wi * si + xr;
                    const float ti = wr * si + wi * sr + xi;
                    sr = tr; si = ti;
                }
                #pragma unroll
                for (int j = 0; j < 8; ++j) va[j] = vb[j];
            }
            if ((t & 1) == 0) {
                pa = make_float2(sr, si);
            } else {
                const float cr2 = W32r * pa.x - W32i * pa.y + sr;
                const float ci2 = W32r * pa.y + W32i * pa.x + si;
                part[((size_t)b * 32 + 2 * seg + (t >> 1)) * NP + tid] =
                    make_float2(cr2, ci2);
            }
        }
    }
}

// ---------------------------------------------------------------------------
// s2: scan 64-l chunk carries -> state ENTERING each chunk (w^64 composition).
// ---------------------------------------------------------------------------
__global__ __launch_bounds__(256) void s2(
    const float2* __restrict__ part, const float* __restrict__ logLr,
    const float* __restrict__ Lim, const float* __restrict__ logDt,
    float2* __restrict__ C)
{
    const int b = blockIdx.x, p = threadIdx.x;
    float wr, wi; discretize(logLr, Lim, logDt, p, wr, wi);
    float Wr = wr, Wi = wi;
    #pragma unroll
    for (int t = 0; t < 6; ++t) { const float r = Wr * Wr - Wi * Wi; Wi = 2.f * Wr * Wi; Wr = r; }  // w^64
    float sr = 0.f, si = 0.f;
    for (int m = 0; m < 32; ++m) {
        C[(size_t)(b * 32 + m) * NP + p] = make_float2(sr, si);
        const float2 v = part[(size_t)(b * 32 + m) * NP + p];
        const float tr = Wr * sr - Wi * si + v.x;
        const float ti = Wr * si + Wi * sr + v.y;
        sr = tr; si = ti;
    }
}

// ---------------------------------------------------------------------------
// gB: fused scan-replay + output GEMM per (b, 64-l chunk), p-SPLIT into two
// 256-p' halves (r3-verified structure: 50.4 us, VGPR=64, no spill).
// ---------------------------------------------------------------------------
__global__ __launch_bounds__(256, 4) void gB(
    const unsigned* __restrict__ bu32, const unsigned short* __restrict__ ChatF,
    const float* __restrict__ logLr, const float* __restrict__ Lim,
    const float* __restrict__ logDt, const float2* __restrict__ C,
    const float* __restrict__ Dv, const float* __restrict__ u,
    float* __restrict__ out)
{
    __shared__ char   osb[32768];          // o half-tile [64 l][256 shorts], swizzled
    __shared__ float2 carr[2][3 * 128];    // per-half carries of waves 0..2 (6 KiB)

    const int m = blockIdx.x, b = blockIdx.y;
    const int tid = threadIdx.x;
    const int w = tid >> 6, lane = tid & 63;
    const int q = lane >> 4, c = lane & 15;
    const int wm = w >> 1, wn = w & 1;
    const int hbase = wm * 64;
    const int lbase = m * 64 + wn * 32;

    f32x4 acc[4][2];
    #pragma unroll
    for (int mt = 0; mt < 4; ++mt)
        #pragma unroll
        for (int nt = 0; nt < 2; ++nt) acc[mt][nt] = (f32x4){0.f, 0.f, 0.f, 0.f};

    #pragma unroll 1
    for (int half = 0; half < 2; ++half) {
        const int pc0 = half * 128 + lane * 2;   // lane's two complex p: pc0, pc0+1

        float wr[2], wi[2];
        #pragma unroll
        for (int e = 0; e < 2; ++e) discretize(logLr, Lim, logDt, pc0 + e, wr[e], wi[e]);

        // W16 = w^16 (4 squarings)
        float Wr[2], Wi[2];
        #pragma unroll
        for (int e = 0; e < 2; ++e) { Wr[e] = wr[e]; Wi[e] = wi[e]; }
        #pragma unroll
        for (int t = 0; t < 4; ++t)
            #pragma unroll
            for (int e = 0; e < 2; ++e) {
                const float r = Wr[e] * Wr[e] - Wi[e] * Wi[e];
                Wi[e] = 2.f * Wr[e] * Wi[e]; Wr[e] = r;
            }

        // this wave's 16 rows, this half's columns (8 B/lane/row, 512 B/row coalesced)
        const unsigned* base = bu32 + ((size_t)(b * SL + m * 64 + w * 16)) * NP
                                    + half * 128 + lane * 2;
        uint2 va[16];
        #pragma unroll
        for (int k = 0; k < 16; ++k) va[k] = *(const uint2*)(base + (size_t)k * NP);

        // pass 1: carry-only local scan (zero entry)
        float sr[2] = {0.f, 0.f}, si[2] = {0.f, 0.f};
        #pragma unroll
        for (int k = 0; k < 16; ++k) {
            unsigned vv[2] = { va[k].x, va[k].y };
            #pragma unroll
            for (int e = 0; e < 2; ++e) {
                const float xr = bf2f((unsigned short)(vv[e] & 0xffffu));
                const float xi = bf2f((unsigned short)(vv[e] >> 16));
                const float tr = wr[e] * sr[e] - wi[e] * si[e] + xr;
                const float ti = wr[e] * si[e] + wi[e] * sr[e] + xi;
                sr[e] = tr; si[e] = ti;
            }
        }
        if (w < 3) {
            #pragma unroll
            for (int e = 0; e < 2; ++e)
                carr[half][w * 128 + lane * 2 + e] = make_float2(sr[e], si[e]);
        }

        // entry state for the whole 64-l chunk
        float Er[2], Ei[2];
        #pragma unroll
        for (int e = 0; e < 2; ++e) {
            const float2 E = C[((size_t)(b * 32 + m)) * NP + pc0 + e];
            Er[e] = E.x; Ei[e] = E.y;
        }

        __syncthreads();                    // carries visible

        // compose true entry: S = E; for j<w: S = W16*S + C_j
        #pragma unroll
        for (int j = 0; j < 3; ++j) if (j < w)
            #pragma unroll
            for (int e = 0; e < 2; ++e) {
                const float2 v = carr[half][j * 128 + lane * 2 + e];
                const float tr = Wr[e] * Er[e] - Wi[e] * Ei[e] + v.x;
                const float ti = Wr[e] * Ei[e] + Wi[e] * Er[e] + v.y;
                Er[e] = tr; Ei[e] = ti;
            }

        // pass 2: exact replay from true entry, pack bf16, swizzled LDS store
        #pragma unroll
        for (int e = 0; e < 2; ++e) { sr[e] = Er[e]; si[e] = Ei[e]; }
        #pragma unroll
        for (int k = 0; k < 16; ++k) {
            unsigned vv[2] = { va[k].x, va[k].y };
            unsigned ov[2];
            #pragma unroll
            for (int e = 0; e < 2; ++e) {
                const float xr = bf2f((unsigned short)(vv[e] & 0xffffu));
                const float xi = bf2f((unsigned short)(vv[e] >> 16));
                const float tr = wr[e] * sr[e] - wi[e] * si[e] + xr;
                const float ti = wr[e] * si[e] + wi[e] * sr[e] + xi;
                sr[e] = tr; si[e] = ti;
                ov[e] = (unsigned)f2bf(tr) | ((unsigned)f2bf(ti) << 16);
            }
            const int row = w * 16 + k;     // row & 7 == k & 7
            const unsigned byte = (((unsigned)row << 9) + ((unsigned)lane << 3))
                                  ^ (((unsigned)(row & 7)) << 4);
            uint2 st = { ov[0], ov[1] };
            *(uint2*)(osb + byte) = st;
        }
        __syncthreads();                    // os half-tile ready

        // GEMM this half's 8 kk (acc accumulates across halves)
        #pragma unroll 4
        for (int kl = 0; kl < 8; ++kl) {
            const int kk = half * 8 + kl;
            bf16x8 af[4];
            #pragma unroll
            for (int mt = 0; mt < 4; ++mt)
                af[mt] = *(const bf16x8*)(ChatF + ((size_t)kk << 12)
                                          + ((hbase + (mt << 4) + c) << 5) + (q << 3));
            bf16x8 bfr[2];
            #pragma unroll
            for (int nt = 0; nt < 2; ++nt) {
                const int r = wn * 32 + 16 * nt + c;   // r & 7 == c & 7
                const unsigned byte = (((unsigned)r << 9) + ((unsigned)kl << 6)
                                       + ((unsigned)q << 4))
                                      ^ (((unsigned)(c & 7)) << 4);
                bfr[nt] = *(const bf16x8*)(osb + byte);
            }
            #pragma unroll
            for (int mt = 0; mt < 4; ++mt)
                #pragma unroll
                for (int nt = 0; nt < 2; ++nt)
                    acc[mt][nt] = __builtin_amdgcn_mfma_f32_16x16x32_bf16(
                        af[mt], bfr[nt], acc[mt][nt], 0, 0, 0);
        }
        if (half == 0) __syncthreads();     // os consumed before overwrite
    }

    #pragma unroll
    for (int mt = 0; mt < 4; ++mt) {
        const int h4 = hbase + 16 * mt + 4 * q;
        const float4 dd = *(const float4*)(Dv + h4);
        #pragma unroll
        for (int nt = 0; nt < 2; ++nt) {
            const int l = lbase + 16 * nt + c;
            const size_t off = ((size_t)l * NB + b) * NH + h4;
            const float4 uu = *(const float4*)(u + off);
            float4 ov;
            ov.x = acc[mt][nt][0] + dd.x * uu.x;
            ov.y = acc[mt][nt][1] + dd.y * uu.y;
            ov.z = acc[mt][nt][2] + dd.z * uu.z;
            ov.w = acc[mt][nt][3] + dd.w * uu.w;
            *(float4*)(out + off) = ov;
        }
    }
}

extern "C" void kernel_launch(void* const* d_in, const int* in_sizes, int n_in,
                              void* d_out, int out_size, void* d_ws, size_t ws_size,
                              hipStream_t stream)
{
    const float* u     = (const float*)d_in[0];
    const float* logLr = (const float*)d_in[1];
    const float* Lim   = (const float*)d_in[2];
    const float* Btr   = (const float*)d_in[3];
    const float* Bti   = (const float*)d_in[4];
    const float* Ctr   = (const float*)d_in[5];
    const float* Cti   = (const float*)d_in[6];
    const float* Dv    = (const float*)d_in[7];
    const float* logDt = (const float*)d_in[8];
    float* out = (float*)d_out;

    char* ws = (char*)d_ws;
    unsigned short* bu   = (unsigned short*)ws;                  // 67,108,864 B
    float2*         part = (float2*)(ws + 67108864);             //  2,097,152 B
    float2*         Cst  = (float2*)(ws + 69206016);             //  2,097,152 B
    unsigned short* Bhat = (unsigned short*)(ws + 71303168);     //    131,072 B (BhatF)
    unsigned short* Chat = (unsigned short*)(ws + 71434240);     //    131,072 B (ChatF)

    k0<<<dim3((NP * NH) / 256), 256, 0, stream>>>(logLr, Lim, logDt,
                                                  Btr, Bti, Ctr, Cti, Bhat, Chat);
    gA<<<dim3(16, NB), 256, 0, stream>>>(u, Bhat, logLr, Lim, logDt, bu, part);
    s2<<<dim3(NB), 256, 0, stream>>>(part, logLr, Lim, logDt, Cst);
    gB<<<dim3(SL / 64, NB), 256, 0, stream>>>((const unsigned*)bu, Chat, logLr, Lim,
                                              logDt, Cst, Dv, u, out);
}

// Round 6
// 182.892 us; speedup vs baseline: 1.2531x; 1.2531x over previous
//
#include <hip/hip_runtime.h>
#include <math.h>

#define SL 2048   // sequence length L
#define NB 32     // batch
#define NH 128    // feature dim H
#define NP 256    // state dim P (complex)
#define NP2 512   // interleaved real/imag columns

typedef short bf16x8 __attribute__((ext_vector_type(8)));
typedef float f32x4  __attribute__((ext_vector_type(4)));

static __device__ __forceinline__ unsigned short f2bf(float x) {
    unsigned u = __float_as_uint(x);
    return (unsigned short)((u + 0x7fffu + ((u >> 16) & 1u)) >> 16);  // RNE
}
static __device__ __forceinline__ float bf2f(unsigned short h) {
    return __uint_as_float(((unsigned)h) << 16);
}
static __device__ __forceinline__ void discretize(
    const float* __restrict__ logLr, const float* __restrict__ Lim,
    const float* __restrict__ logDt, int p, float& wr, float& wi)
{
    const float Lr = expf(logLr[p]);
    const float dt = expf(logDt[p]);
    const float ew = expf(-Lr * dt);
    const float ang = Lim[p] * dt;
    wr = ew * cosf(ang); wi = ew * sinf(ang);
}

// ---------------------------------------------------------------------------
// k0: pack Bhat[p'=512][h=128] = f_p * B_tilde (bf16, row-major: gA keeps
// persistent A-fragments in VGPRs) and ChatF[kk=0..15][h=0..127][32],
// fragment-major [Cr,-Ci] so gB's af loads are contiguous 1 KB/wave.
// ---------------------------------------------------------------------------
__global__ __launch_bounds__(256) void k0(
    const float* __restrict__ logLr, const float* __restrict__ Lim,
    const float* __restrict__ logDt,
    const float* __restrict__ Br, const float* __restrict__ Bi,
    const float* __restrict__ Cr, const float* __restrict__ Ci,
    unsigned short* __restrict__ Bhat, unsigned short* __restrict__ ChatF)
{
    const int tid = blockIdx.x * 256 + threadIdx.x;  // 32768 = P*H
    const int p = tid >> 7, h = tid & 127;
    float wr, wi; discretize(logLr, Lim, logDt, p, wr, wi);
    const float Lr = expf(logLr[p]), li = Lim[p];
    const float nr = wr - 1.0f, ni = wi;
    const float den = Lr * Lr + li * li;
    const float fr = (-nr * Lr + ni * li) / den;
    const float fi = (-ni * Lr - nr * li) / den;
    const float br = Br[p * NH + h], bi = Bi[p * NH + h];
    Bhat[(size_t)(2 * p)     * NH + h] = f2bf(fr * br - fi * bi);
    Bhat[(size_t)(2 * p + 1) * NH + h] = f2bf(fr * bi + fi * br);
    const int col0 = 2 * p, col1 = 2 * p + 1;
    ChatF[((size_t)(col0 >> 5) << 12) + (h << 5) + (col0 & 31)] = f2bf(Cr[h * NP + p]);
    ChatF[((size_t)(col1 >> 5) << 12) + (h << 5) + (col1 & 31)] = f2bf(-Ci[h * NP + p]);
}

// ---------------------------------------------------------------------------
// gA: GEMM1 with per-wave persistent A-fragments (128 VGPR, (256,2): NO
// tighter bound — spill cliff proven in r4/r5) + bu store + raw 32-l carries.
// ---------------------------------------------------------------------------
__global__ __launch_bounds__(256, 2) void gA(
    const float* __restrict__ u, const unsigned short* __restrict__ Bhat,
    const float* __restrict__ logLr, const float* __restrict__ Lim,
    const float* __restrict__ logDt,
    unsigned short* __restrict__ bu, float2* __restrict__ part)
{
    __shared__ unsigned short us[32][136];   // u tile bf16 [l][h], pad 8
    __shared__ unsigned xs[32 * 257];        // out tile [l][complex p], pitch 257

    const int seg = blockIdx.x;              // 0..15
    const int b   = blockIdx.y;
    const int tid = threadIdx.x;
    const int wave = tid >> 6, lane = tid & 63;
    const int q = lane >> 4, c = lane & 15;
    const int pbase = wave * 128;

    // persistent A fragments: 32 x bf16x8 = 128 VGPRs
    bf16x8 A[4][8];
    #pragma unroll
    for (int kk = 0; kk < 4; ++kk)
        #pragma unroll
        for (int mt = 0; mt < 8; ++mt)
            A[kk][mt] = *(const bf16x8*)(Bhat + (size_t)(pbase + 16 * mt + c) * NH
                                              + kk * 32 + 8 * q);

    // scan constants for this thread's p = tid
    float wr, wi; discretize(logLr, Lim, logDt, tid, wr, wi);

    for (int t = 0; t < 4; ++t) {
        const int l0 = seg * 128 + t * 32;
        __syncthreads();   // prev scan / us reads done
        {   // stage u tile (32 l x 128 h) fp32 -> bf16 LDS
            const int lrow = tid >> 3;
            const int hcol = (tid & 7) * 16;
            const float* up = u + (size_t)(l0 + lrow) * (NB * NH) + b * NH + hcol;
            float4 a = *(const float4*)(up + 0);
            float4 d = *(const float4*)(up + 4);
            float4 e = *(const float4*)(up + 8);
            float4 g = *(const float4*)(up + 12);
            uint4 w0, w1;
            w0.x = (unsigned)f2bf(a.x) | ((unsigned)f2bf(a.y) << 16);
            w0.y = (unsigned)f2bf(a.z) | ((unsigned)f2bf(a.w) << 16);
            w0.z = (unsigned)f2bf(d.x) | ((unsigned)f2bf(d.y) << 16);
            w0.w = (unsigned)f2bf(d.z) | ((unsigned)f2bf(d.w) << 16);
            w1.x = (unsigned)f2bf(e.x) | ((unsigned)f2bf(e.y) << 16);
            w1.y = (unsigned)f2bf(e.z) | ((unsigned)f2bf(e.w) << 16);
            w1.z = (unsigned)f2bf(g.x) | ((unsigned)f2bf(g.y) << 16);
            w1.w = (unsigned)f2bf(g.z) | ((unsigned)f2bf(g.w) << 16);
            *(uint4*)&us[lrow][hcol + 0] = w0;
            *(uint4*)&us[lrow][hcol + 8] = w1;
        }
        __syncthreads();

        f32x4 acc[8][2];
        #pragma unroll
        for (int mt = 0; mt < 8; ++mt)
            #pragma unroll
            for (int nt = 0; nt < 2; ++nt) acc[mt][nt] = (f32x4){0.f, 0.f, 0.f, 0.f};

        #pragma unroll
        for (int kk = 0; kk < 4; ++kk) {
            bf16x8 bfr[2];
            #pragma unroll
            for (int nt = 0; nt < 2; ++nt)
                bfr[nt] = *(const bf16x8*)&us[16 * nt + c][kk * 32 + 8 * q];
            #pragma unroll
            for (int mt = 0; mt < 8; ++mt)
                #pragma unroll
                for (int nt = 0; nt < 2; ++nt)
                    acc[mt][nt] = __builtin_amdgcn_mfma_f32_16x16x32_bf16(
                        A[kk][mt], bfr[nt], acc[mt][nt], 0, 0, 0);
        }

        // store bu + stash xs
        #pragma unroll
        for (int mt = 0; mt < 8; ++mt)
            #pragma unroll
            for (int nt = 0; nt < 2; ++nt) {
                const int rw = 16 * nt + c;               // local l row
                const int pp = pbase + 16 * mt + 4 * q;   // p' base
                ushort4 st;
                st.x = f2bf(acc[mt][nt][0]); st.y = f2bf(acc[mt][nt][1]);
                st.z = f2bf(acc[mt][nt][2]); st.w = f2bf(acc[mt][nt][3]);
                *(ushort4*)(bu + ((size_t)(b * SL + l0 + rw)) * NP2 + pp) = st;
                const int col = (pp >> 1);                // complex index
                xs[rw * 257 + col]     = (unsigned)st.x | ((unsigned)st.y << 16);
                xs[rw * 257 + col + 1] = (unsigned)st.z | ((unsigned)st.w << 16);
            }
        __syncthreads();

        // carry-only scan of column p = tid over 32 rows -> raw 32-l carry
        {
            float sr = 0.f, si = 0.f;
            unsigned va[8], vb[8];
            #pragma unroll
            for (int j = 0; j < 8; ++j) va[j] = xs[j * 257 + tid];
            #pragma unroll
            for (int k8 = 0; k8 < 4; ++k8) {
                if (k8 < 3) {
                    #pragma unroll
                    for (int j = 0; j < 8; ++j) vb[j] = xs[((k8 + 1) * 8 + j) * 257 + tid];
                }
                #pragma unroll
                for (int j = 0; j < 8; ++j) {
                    const float xr = bf2f((unsigned short)(va[j] & 0xffffu));
                    const float xi = bf2f((unsigned short)(va[j] >> 16));
                    const float tr = wr * sr - wi * si + xr;
                    const float ti = wr * si + wi * sr + xi;
                    sr = tr; si = ti;
                }
                #pragma unroll
                for (int j = 0; j < 8; ++j) va[j] = vb[j];
            }
            part[((size_t)b * 64 + seg * 4 + t) * NP + tid] = make_float2(sr, si);
        }
    }
}

// ---------------------------------------------------------------------------
// s2: in-place scan of 32-l tile carries -> state ENTERING each tile,
// composed with W32 = w^32. NEW: 8-deep prefetch so the 64 dependent global
// loads pipeline instead of serializing the scan chain at memory latency.
// ---------------------------------------------------------------------------
__global__ __launch_bounds__(256) void s2(
    float2* __restrict__ part, const float* __restrict__ logLr,
    const float* __restrict__ Lim, const float* __restrict__ logDt)
{
    const int b = blockIdx.x, p = threadIdx.x;
    float wr, wi; discretize(logLr, Lim, logDt, p, wr, wi);
    float Wr = wr, Wi = wi;
    #pragma unroll
    for (int t = 0; t < 5; ++t) { const float r = Wr * Wr - Wi * Wi; Wi = 2.f * Wr * Wi; Wr = r; }  // w^32
    const size_t base = (size_t)b * 64 * NP + p;
    float sr = 0.f, si = 0.f;
    float2 va[8], vb[8];
    #pragma unroll
    for (int j = 0; j < 8; ++j) va[j] = part[base + (size_t)j * NP];
    #pragma unroll
    for (int k8 = 0; k8 < 8; ++k8) {
        if (k8 < 7) {
            #pragma unroll
            for (int j = 0; j < 8; ++j)
                vb[j] = part[base + (size_t)((k8 + 1) * 8 + j) * NP];
        }
        #pragma unroll
        for (int j = 0; j < 8; ++j) {
            part[base + (size_t)(k8 * 8 + j) * NP] = make_float2(sr, si);  // entry
            const float tr = Wr * sr - Wi * si + va[j].x;
            const float ti = Wr * si + Wi * sr + va[j].y;
            sr = tr; si = ti;
        }
        #pragma unroll
        for (int j = 0; j < 8; ++j) va[j] = vb[j];
    }
}

// ---------------------------------------------------------------------------
// gB: fused scan-replay + output GEMM per (b, 32-l chunk). Grid 2048 blocks;
// LDS = 16 KiB tile + 3 KiB carries = 19456 B. launch_bounds(256,4) — the
// bound r3-gB compiled at VGPR=64 with NO spill; r4's (256,8) forced VGPR=32
// and spilled (WRITE 97 MB). With ~56-64 VGPR + 19.4 KB LDS the HW allows
// 8 blocks/CU residency.
// Per half (256 p'): 4 waves x 8 rows scan (lane owns 2 complex), carry
// exchange, W8 compose from the 32-l entry, exact f32 replay -> swizzled LDS,
// GEMM over that half's 8 kk (acc persists across halves). Wave = h-quadrant.
// ---------------------------------------------------------------------------
__global__ __launch_bounds__(256, 4) void gB(
    const unsigned* __restrict__ bu32, const unsigned short* __restrict__ ChatF,
    const float* __restrict__ logLr, const float* __restrict__ Lim,
    const float* __restrict__ logDt, const float2* __restrict__ Ent,
    const float* __restrict__ Dv, const float* __restrict__ u,
    float* __restrict__ out)
{
    __shared__ char   osb[16384];          // o half-tile [32 l][256 shorts], swizzled
    __shared__ float2 carr[3 * 128];       // carries of waves 0..2 (reused per half)

    const int m = blockIdx.x, b = blockIdx.y;   // m: 32-l chunk, 0..63
    const int tid = threadIdx.x;
    const int w = tid >> 6, lane = tid & 63;
    const int q = lane >> 4, c = lane & 15;
    const int hbase = w * 32;              // wave owns a 32-h quadrant
    const int lbase = m * 32;

    f32x4 acc[2][2];
    #pragma unroll
    for (int mt = 0; mt < 2; ++mt)
        #pragma unroll
        for (int nt = 0; nt < 2; ++nt) acc[mt][nt] = (f32x4){0.f, 0.f, 0.f, 0.f};

    #pragma unroll 1
    for (int half = 0; half < 2; ++half) {
        const int pc0 = half * 128 + lane * 2;   // lane's two complex p

        float wr[2], wi[2];
        #pragma unroll
        for (int e = 0; e < 2; ++e) discretize(logLr, Lim, logDt, pc0 + e, wr[e], wi[e]);

        // W8 = w^8 (3 squarings)
        float Wr[2], Wi[2];
        #pragma unroll
        for (int e = 0; e < 2; ++e) { Wr[e] = wr[e]; Wi[e] = wi[e]; }
        #pragma unroll
        for (int t = 0; t < 3; ++t)
            #pragma unroll
            for (int e = 0; e < 2; ++e) {
                const float r = Wr[e] * Wr[e] - Wi[e] * Wi[e];
                Wi[e] = 2.f * Wr[e] * Wi[e]; Wr[e] = r;
            }

        // this wave's 8 rows, this half's columns (8 B/lane/row, 512 B/row)
        const unsigned* base = bu32 + ((size_t)(b * SL + m * 32 + w * 8)) * NP
                                    + half * 128 + lane * 2;
        uint2 va[8];
        #pragma unroll
        for (int k = 0; k < 8; ++k) va[k] = *(const uint2*)(base + (size_t)k * NP);

        // pass 1: carry-only local scan (zero entry)
        float sr[2] = {0.f, 0.f}, si[2] = {0.f, 0.f};
        #pragma unroll
        for (int k = 0; k < 8; ++k) {
            unsigned vv[2] = { va[k].x, va[k].y };
            #pragma unroll
            for (int e = 0; e < 2; ++e) {
                const float xr = bf2f((unsigned short)(vv[e] & 0xffffu));
                const float xi = bf2f((unsigned short)(vv[e] >> 16));
                const float tr = wr[e] * sr[e] - wi[e] * si[e] + xr;
                const float ti = wr[e] * si[e] + wi[e] * sr[e] + xi;
                sr[e] = tr; si[e] = ti;
            }
        }
        if (w < 3) {
            #pragma unroll
            for (int e = 0; e < 2; ++e)
                carr[w * 128 + lane * 2 + e] = make_float2(sr[e], si[e]);
        }

        // entry state for this 32-l chunk
        float Er[2], Ei[2];
        #pragma unroll
        for (int e = 0; e < 2; ++e) {
            const float2 E = Ent[((size_t)(b * 64 + m)) * NP + pc0 + e];
            Er[e] = E.x; Ei[e] = E.y;
        }

        __syncthreads();                    // carries visible

        // compose true entry: S = E; for j<w: S = W8*S + C_j
        #pragma unroll
        for (int j = 0; j < 3; ++j) if (j < w)
            #pragma unroll
            for (int e = 0; e < 2; ++e) {
                const float2 v = carr[j * 128 + lane * 2 + e];
                const float tr = Wr[e] * Er[e] - Wi[e] * Ei[e] + v.x;
                const float ti = Wr[e] * Ei[e] + Wi[e] * Er[e] + v.y;
                Er[e] = tr; Ei[e] = ti;
            }

        // pass 2: exact replay from true entry, pack bf16, swizzled LDS store
        #pragma unroll
        for (int e = 0; e < 2; ++e) { sr[e] = Er[e]; si[e] = Ei[e]; }
        #pragma unroll
        for (int k = 0; k < 8; ++k) {
            unsigned vv[2] = { va[k].x, va[k].y };
            unsigned ov[2];
            #pragma unroll
            for (int e = 0; e < 2; ++e) {
                const float xr = bf2f((unsigned short)(vv[e] & 0xffffu));
                const float xi = bf2f((unsigned short)(vv[e] >> 16));
                const float tr = wr[e] * sr[e] - wi[e] * si[e] + xr;
                const float ti = wr[e] * si[e] + wi[e] * sr[e] + xi;
                sr[e] = tr; si[e] = ti;
                ov[e] = (unsigned)f2bf(tr) | ((unsigned)f2bf(ti) << 16);
            }
            const int row = w * 8 + k;      // row & 7 == k & 7
            const unsigned byte = (((unsigned)row << 9) + ((unsigned)lane << 3))
                                  ^ (((unsigned)(row & 7)) << 4);
            uint2 st = { ov[0], ov[1] };
            *(uint2*)(osb + byte) = st;
        }
        __syncthreads();                    // os half-tile ready

        // GEMM this half's 8 kk (acc accumulates across halves)
        #pragma unroll 4
        for (int kl = 0; kl < 8; ++kl) {
            const int kk = half * 8 + kl;
            bf16x8 af[2];
            #pragma unroll
            for (int mt = 0; mt < 2; ++mt)
                af[mt] = *(const bf16x8*)(ChatF + ((size_t)kk << 12)
                                          + ((hbase + (mt << 4) + c) << 5) + (q << 3));
            bf16x8 bfr[2];
            #pragma unroll
            for (int nt = 0; nt < 2; ++nt) {
                const int r = 16 * nt + c;           // r & 7 == c & 7
                const unsigned byte = (((unsigned)r << 9) + ((unsigned)kl << 6)
                                       + ((unsigned)q << 4))
                                      ^ (((unsigned)(c & 7)) << 4);
                bfr[nt] = *(const bf16x8*)(osb + byte);
            }
            #pragma unroll
            for (int mt = 0; mt < 2; ++mt)
                #pragma unroll
                for (int nt = 0; nt < 2; ++nt)
                    acc[mt][nt] = __builtin_amdgcn_mfma_f32_16x16x32_bf16(
                        af[mt], bfr[nt], acc[mt][nt], 0, 0, 0);
        }
        if (half == 0) __syncthreads();     // os + carr consumed before overwrite
    }

    #pragma unroll
    for (int mt = 0; mt < 2; ++mt) {
        const int h4 = hbase + 16 * mt + 4 * q;
        const float4 dd = *(const float4*)(Dv + h4);
        #pragma unroll
        for (int nt = 0; nt < 2; ++nt) {
            const int l = lbase + 16 * nt + c;
            const size_t off = ((size_t)l * NB + b) * NH + h4;
            const float4 uu = *(const float4*)(u + off);
            float4 ov;
            ov.x = acc[mt][nt][0] + dd.x * uu.x;
            ov.y = acc[mt][nt][1] + dd.y * uu.y;
            ov.z = acc[mt][nt][2] + dd.z * uu.z;
            ov.w = acc[mt][nt][3] + dd.w * uu.w;
            *(float4*)(out + off) = ov;
        }
    }
}

extern "C" void kernel_launch(void* const* d_in, const int* in_sizes, int n_in,
                              void* d_out, int out_size, void* d_ws, size_t ws_size,
                              hipStream_t stream)
{
    const float* u     = (const float*)d_in[0];
    const float* logLr = (const float*)d_in[1];
    const float* Lim   = (const float*)d_in[2];
    const float* Btr   = (const float*)d_in[3];
    const float* Bti   = (const float*)d_in[4];
    const float* Ctr   = (const float*)d_in[5];
    const float* Cti   = (const float*)d_in[6];
    const float* Dv    = (const float*)d_in[7];
    const float* logDt = (const float*)d_in[8];
    float* out = (float*)d_out;

    char* ws = (char*)d_ws;
    unsigned short* bu   = (unsigned short*)ws;                  // 67,108,864 B
    float2*         part = (float2*)(ws + 67108864);             //  4,194,304 B (carries -> entries in place)
    unsigned short* Bhat = (unsigned short*)(ws + 71303168);     //    131,072 B
    unsigned short* Chat = (unsigned short*)(ws + 71434240);     //    131,072 B (ChatF)

    k0<<<dim3((NP * NH) / 256), 256, 0, stream>>>(logLr, Lim, logDt,
                                                  Btr, Bti, Ctr, Cti, Bhat, Chat);
    gA<<<dim3(16, NB), 256, 0, stream>>>(u, Bhat, logLr, Lim, logDt, bu, part);
    s2<<<dim3(NB), 256, 0, stream>>>(part, logLr, Lim, logDt);
    gB<<<dim3(SL / 32, NB), 256, 0, stream>>>((const unsigned*)bu, Chat, logLr, Lim,
                                              logDt, part, Dv, u, out);
}

// Round 7
// 176.800 us; speedup vs baseline: 1.2963x; 1.0345x over previous
//
#include <hip/hip_runtime.h>
#include <math.h>

#define SL 2048   // sequence length L
#define NB 32     // batch
#define NH 128    // feature dim H
#define NP 256    // state dim P (complex)
#define NP2 512   // interleaved real/imag columns

typedef short bf16x8 __attribute__((ext_vector_type(8)));
typedef float f32x4  __attribute__((ext_vector_type(4)));

static __device__ __forceinline__ unsigned short f2bf(float x) {
    unsigned u = __float_as_uint(x);
    return (unsigned short)((u + 0x7fffu + ((u >> 16) & 1u)) >> 16);  // RNE
}
static __device__ __forceinline__ float bf2f(unsigned short h) {
    return __uint_as_float(((unsigned)h) << 16);
}
static __device__ __forceinline__ void discretize(
    const float* __restrict__ logLr, const float* __restrict__ Lim,
    const float* __restrict__ logDt, int p, float& wr, float& wi)
{
    const float Lr = expf(logLr[p]);
    const float dt = expf(logDt[p]);
    const float ew = expf(-Lr * dt);
    const float ang = Lim[p] * dt;
    wr = ew * cosf(ang); wi = ew * sinf(ang);
}

// ---------------------------------------------------------------------------
// k0: pack BhatF, fragment-major f_p*B_tilde: BhatF[(h>>5)<<14 | p'<<5 | h&31]
// so a gA wave's af load (lane=(q,c)) is one contiguous coalesced 1 KB.
// ChatF[kk=0..15][h=0..127][32] = fragment-major [Cr,-Ci] for gB.
// ---------------------------------------------------------------------------
__global__ __launch_bounds__(256) void k0(
    const float* __restrict__ logLr, const float* __restrict__ Lim,
    const float* __restrict__ logDt,
    const float* __restrict__ Br, const float* __restrict__ Bi,
    const float* __restrict__ Cr, const float* __restrict__ Ci,
    unsigned short* __restrict__ BhatF, unsigned short* __restrict__ ChatF)
{
    const int tid = blockIdx.x * 256 + threadIdx.x;  // 32768 = P*H
    const int p = tid >> 7, h = tid & 127;
    float wr, wi; discretize(logLr, Lim, logDt, p, wr, wi);
    const float Lr = expf(logLr[p]), li = Lim[p];
    const float nr = wr - 1.0f, ni = wi;
    const float den = Lr * Lr + li * li;
    const float fr = (-nr * Lr + ni * li) / den;
    const float fi = (-ni * Lr - nr * li) / den;
    const float br = Br[p * NH + h], bi = Bi[p * NH + h];
    BhatF[((size_t)(h >> 5) << 14) + ((2 * p)     << 5) + (h & 31)] = f2bf(fr * br - fi * bi);
    BhatF[((size_t)(h >> 5) << 14) + ((2 * p + 1) << 5) + (h & 31)] = f2bf(fr * bi + fi * br);
    const int col0 = 2 * p, col1 = 2 * p + 1;
    ChatF[((size_t)(col0 >> 5) << 12) + (h << 5) + (col0 & 31)] = f2bf(Cr[h * NP + p]);
    ChatF[((size_t)(col1 >> 5) << 12) + (h << 5) + (col1 & 31)] = f2bf(-Ci[h * NP + p]);
}

// ---------------------------------------------------------------------------
// gA: ONE independent 32-l x 256-p' tile per block (grid 64 x 2 x 32 = 4096
// blocks). No persistent A (af streamed from L2-resident BhatF, coalesced
// 1 KB/fragment), acc[4][2] (32 f32), LDS 25.2 KB, 2 barriers, no cross-tile
// serialization. (256,4) — the only proven-spill-free bound (r3/r6 gB);
// r4/r5's tighter bounds forced VGPR 32/64 and spilled 2x.
// Raw 32-l carry per (chunk, p) written to part (scan math unchanged).
// ---------------------------------------------------------------------------
__global__ __launch_bounds__(256, 4) void gA(
    const float* __restrict__ u, const unsigned short* __restrict__ BhatF,
    const float* __restrict__ logLr, const float* __restrict__ Lim,
    const float* __restrict__ logDt,
    unsigned short* __restrict__ bu, float2* __restrict__ part)
{
    __shared__ unsigned short us[32][136];   // u tile bf16 [l][h], pad 8 (8704 B)
    __shared__ unsigned xs[32 * 129];        // out tile [l][128 complex], pitch 129 (16512 B)

    const int m  = blockIdx.x;               // 32-l chunk, 0..63
    const int ph = blockIdx.y;               // p-half, 0..1
    const int b  = blockIdx.z;
    const int tid = threadIdx.x;
    const int w = tid >> 6, lane = tid & 63;
    const int q = lane >> 4, c = lane & 15;
    const int pbase = ph * 256 + w * 64;     // wave's 64 p' (global)
    const int l0 = m * 32;

    {   // stage u tile (32 l x 128 h) fp32 -> bf16 LDS
        const int lrow = tid >> 3;
        const int hcol = (tid & 7) * 16;
        const float* up = u + (size_t)(l0 + lrow) * (NB * NH) + b * NH + hcol;
        float4 a = *(const float4*)(up + 0);
        float4 d = *(const float4*)(up + 4);
        float4 e = *(const float4*)(up + 8);
        float4 g = *(const float4*)(up + 12);
        uint4 w0, w1;
        w0.x = (unsigned)f2bf(a.x) | ((unsigned)f2bf(a.y) << 16);
        w0.y = (unsigned)f2bf(a.z) | ((unsigned)f2bf(a.w) << 16);
        w0.z = (unsigned)f2bf(d.x) | ((unsigned)f2bf(d.y) << 16);
        w0.w = (unsigned)f2bf(d.z) | ((unsigned)f2bf(d.w) << 16);
        w1.x = (unsigned)f2bf(e.x) | ((unsigned)f2bf(e.y) << 16);
        w1.y = (unsigned)f2bf(e.z) | ((unsigned)f2bf(e.w) << 16);
        w1.z = (unsigned)f2bf(g.x) | ((unsigned)f2bf(g.y) << 16);
        w1.w = (unsigned)f2bf(g.z) | ((unsigned)f2bf(g.w) << 16);
        *(uint4*)&us[lrow][hcol + 0] = w0;
        *(uint4*)&us[lrow][hcol + 8] = w1;
    }
    __syncthreads();   // us ready

    f32x4 acc[4][2];
    #pragma unroll
    for (int mt = 0; mt < 4; ++mt)
        #pragma unroll
        for (int nt = 0; nt < 2; ++nt) acc[mt][nt] = (f32x4){0.f, 0.f, 0.f, 0.f};

    #pragma unroll
    for (int kk = 0; kk < 4; ++kk) {
        bf16x8 af[4];
        #pragma unroll
        for (int mt = 0; mt < 4; ++mt)
            af[mt] = *(const bf16x8*)(BhatF + ((size_t)kk << 14)
                                      + ((pbase + 16 * mt + c) << 5) + 8 * q);
        bf16x8 bfr[2];
        #pragma unroll
        for (int nt = 0; nt < 2; ++nt)
            bfr[nt] = *(const bf16x8*)&us[16 * nt + c][kk * 32 + 8 * q];
        #pragma unroll
        for (int mt = 0; mt < 4; ++mt)
            #pragma unroll
            for (int nt = 0; nt < 2; ++nt)
                acc[mt][nt] = __builtin_amdgcn_mfma_f32_16x16x32_bf16(
                    af[mt], bfr[nt], acc[mt][nt], 0, 0, 0);
    }

    // store bu + stash xs (xs/us are disjoint buffers: no barrier needed here)
    #pragma unroll
    for (int mt = 0; mt < 4; ++mt)
        #pragma unroll
        for (int nt = 0; nt < 2; ++nt) {
            const int rw  = 16 * nt + c;              // local l row
            const int ppl = w * 64 + 16 * mt + 4 * q; // local p' (0..255)
            const int pp  = ph * 256 + ppl;           // global p'
            ushort4 st;
            st.x = f2bf(acc[mt][nt][0]); st.y = f2bf(acc[mt][nt][1]);
            st.z = f2bf(acc[mt][nt][2]); st.w = f2bf(acc[mt][nt][3]);
            *(ushort4*)(bu + ((size_t)(b * SL + l0 + rw)) * NP2 + pp) = st;
            const int col = (ppl >> 1);               // local complex index 0..127
            xs[rw * 129 + col]     = (unsigned)st.x | ((unsigned)st.y << 16);
            xs[rw * 129 + col + 1] = (unsigned)st.z | ((unsigned)st.w << 16);
        }
    __syncthreads();   // xs ready

    // carry-only scan over 32 rows; threads 0..127 own this half's complex cols
    if (tid < 128) {
        float wr, wi; discretize(logLr, Lim, logDt, ph * 128 + tid, wr, wi);
        float sr = 0.f, si = 0.f;
        unsigned va[8], vb[8];
        #pragma unroll
        for (int j = 0; j < 8; ++j) va[j] = xs[j * 129 + tid];
        #pragma unroll
        for (int k8 = 0; k8 < 4; ++k8) {
            if (k8 < 3) {
                #pragma unroll
                for (int j = 0; j < 8; ++j) vb[j] = xs[((k8 + 1) * 8 + j) * 129 + tid];
            }
            #pragma unroll
            for (int j = 0; j < 8; ++j) {
                const float xr = bf2f((unsigned short)(va[j] & 0xffffu));
                const float xi = bf2f((unsigned short)(va[j] >> 16));
                const float tr = wr * sr - wi * si + xr;
                const float ti = wr * si + wi * sr + xi;
                sr = tr; si = ti;
            }
            #pragma unroll
            for (int j = 0; j < 8; ++j) va[j] = vb[j];
        }
        part[((size_t)b * 64 + m) * NP + ph * 128 + tid] = make_float2(sr, si);
    }
}

// ---------------------------------------------------------------------------
// s2: in-place scan of 32-l tile carries -> state ENTERING each tile,
// composed with W32 = w^32, 8-deep prefetch (r6-proven).
// ---------------------------------------------------------------------------
__global__ __launch_bounds__(256) void s2(
    float2* __restrict__ part, const float* __restrict__ logLr,
    const float* __restrict__ Lim, const float* __restrict__ logDt)
{
    const int b = blockIdx.x, p = threadIdx.x;
    float wr, wi; discretize(logLr, Lim, logDt, p, wr, wi);
    float Wr = wr, Wi = wi;
    #pragma unroll
    for (int t = 0; t < 5; ++t) { const float r = Wr * Wr - Wi * Wi; Wi = 2.f * Wr * Wi; Wr = r; }  // w^32
    const size_t base = (size_t)b * 64 * NP + p;
    float sr = 0.f, si = 0.f;
    float2 va[8], vb[8];
    #pragma unroll
    for (int j = 0; j < 8; ++j) va[j] = part[base + (size_t)j * NP];
    #pragma unroll
    for (int k8 = 0; k8 < 8; ++k8) {
        if (k8 < 7) {
            #pragma unroll
            for (int j = 0; j < 8; ++j)
                vb[j] = part[base + (size_t)((k8 + 1) * 8 + j) * NP];
        }
        #pragma unroll
        for (int j = 0; j < 8; ++j) {
            part[base + (size_t)(k8 * 8 + j) * NP] = make_float2(sr, si);  // entry
            const float tr = Wr * sr - Wi * si + va[j].x;
            const float ti = Wr * si + Wi * sr + va[j].y;
            sr = tr; si = ti;
        }
        #pragma unroll
        for (int j = 0; j < 8; ++j) va[j] = vb[j];
    }
}

// ---------------------------------------------------------------------------
// gB: fused scan-replay + output GEMM per (b, 32-l chunk). r6-exact
// (out of top-5 at (256,4), no spill). Grid 2048; LDS 19456 B.
// ---------------------------------------------------------------------------
__global__ __launch_bounds__(256, 4) void gB(
    const unsigned* __restrict__ bu32, const unsigned short* __restrict__ ChatF,
    const float* __restrict__ logLr, const float* __restrict__ Lim,
    const float* __restrict__ logDt, const float2* __restrict__ Ent,
    const float* __restrict__ Dv, const float* __restrict__ u,
    float* __restrict__ out)
{
    __shared__ char   osb[16384];          // o half-tile [32 l][256 shorts], swizzled
    __shared__ float2 carr[3 * 128];       // carries of waves 0..2 (reused per half)

    const int m = blockIdx.x, b = blockIdx.y;   // m: 32-l chunk, 0..63
    const int tid = threadIdx.x;
    const int w = tid >> 6, lane = tid & 63;
    const int q = lane >> 4, c = lane & 15;
    const int hbase = w * 32;              // wave owns a 32-h quadrant
    const int lbase = m * 32;

    f32x4 acc[2][2];
    #pragma unroll
    for (int mt = 0; mt < 2; ++mt)
        #pragma unroll
        for (int nt = 0; nt < 2; ++nt) acc[mt][nt] = (f32x4){0.f, 0.f, 0.f, 0.f};

    #pragma unroll 1
    for (int half = 0; half < 2; ++half) {
        const int pc0 = half * 128 + lane * 2;   // lane's two complex p

        float wr[2], wi[2];
        #pragma unroll
        for (int e = 0; e < 2; ++e) discretize(logLr, Lim, logDt, pc0 + e, wr[e], wi[e]);

        // W8 = w^8 (3 squarings)
        float Wr[2], Wi[2];
        #pragma unroll
        for (int e = 0; e < 2; ++e) { Wr[e] = wr[e]; Wi[e] = wi[e]; }
        #pragma unroll
        for (int t = 0; t < 3; ++t)
            #pragma unroll
            for (int e = 0; e < 2; ++e) {
                const float r = Wr[e] * Wr[e] - Wi[e] * Wi[e];
                Wi[e] = 2.f * Wr[e] * Wi[e]; Wr[e] = r;
            }

        // this wave's 8 rows, this half's columns (8 B/lane/row, 512 B/row)
        const unsigned* base = bu32 + ((size_t)(b * SL + m * 32 + w * 8)) * NP
                                    + half * 128 + lane * 2;
        uint2 va[8];
        #pragma unroll
        for (int k = 0; k < 8; ++k) va[k] = *(const uint2*)(base + (size_t)k * NP);

        // pass 1: carry-only local scan (zero entry)
        float sr[2] = {0.f, 0.f}, si[2] = {0.f, 0.f};
        #pragma unroll
        for (int k = 0; k < 8; ++k) {
            unsigned vv[2] = { va[k].x, va[k].y };
            #pragma unroll
            for (int e = 0; e < 2; ++e) {
                const float xr = bf2f((unsigned short)(vv[e] & 0xffffu));
                const float xi = bf2f((unsigned short)(vv[e] >> 16));
                const float tr = wr[e] * sr[e] - wi[e] * si[e] + xr;
                const float ti = wr[e] * si[e] + wi[e] * sr[e] + xi;
                sr[e] = tr; si[e] = ti;
            }
        }
        if (w < 3) {
            #pragma unroll
            for (int e = 0; e < 2; ++e)
                carr[w * 128 + lane * 2 + e] = make_float2(sr[e], si[e]);
        }

        // entry state for this 32-l chunk
        float Er[2], Ei[2];
        #pragma unroll
        for (int e = 0; e < 2; ++e) {
            const float2 E = Ent[((size_t)(b * 64 + m)) * NP + pc0 + e];
            Er[e] = E.x; Ei[e] = E.y;
        }

        __syncthreads();                    // carries visible

        // compose true entry: S = E; for j<w: S = W8*S + C_j
        #pragma unroll
        for (int j = 0; j < 3; ++j) if (j < w)
            #pragma unroll
            for (int e = 0; e < 2; ++e) {
                const float2 v = carr[j * 128 + lane * 2 + e];
                const float tr = Wr[e] * Er[e] - Wi[e] * Ei[e] + v.x;
                const float ti = Wr[e] * Ei[e] + Wi[e] * Er[e] + v.y;
                Er[e] = tr; Ei[e] = ti;
            }

        // pass 2: exact replay from true entry, pack bf16, swizzled LDS store
        #pragma unroll
        for (int e = 0; e < 2; ++e) { sr[e] = Er[e]; si[e] = Ei[e]; }
        #pragma unroll
        for (int k = 0; k < 8; ++k) {
            unsigned vv[2] = { va[k].x, va[k].y };
            unsigned ov[2];
            #pragma unroll
            for (int e = 0; e < 2; ++e) {
                const float xr = bf2f((unsigned short)(vv[e] & 0xffffu));
                const float xi = bf2f((unsigned short)(vv[e] >> 16));
                const float tr = wr[e] * sr[e] - wi[e] * si[e] + xr;
                const float ti = wr[e] * si[e] + wi[e] * sr[e] + xi;
                sr[e] = tr; si[e] = ti;
                ov[e] = (unsigned)f2bf(tr) | ((unsigned)f2bf(ti) << 16);
            }
            const int row = w * 8 + k;      // row & 7 == k & 7
            const unsigned byte = (((unsigned)row << 9) + ((unsigned)lane << 3))
                                  ^ (((unsigned)(row & 7)) << 4);
            uint2 st = { ov[0], ov[1] };
            *(uint2*)(osb + byte) = st;
        }
        __syncthreads();                    // os half-tile ready

        // GEMM this half's 8 kk (acc accumulates across halves)
        #pragma unroll 4
        for (int kl = 0; kl < 8; ++kl) {
            const int kk = half * 8 + kl;
            bf16x8 af[2];
            #pragma unroll
            for (int mt = 0; mt < 2; ++mt)
                af[mt] = *(const bf16x8*)(ChatF + ((size_t)kk << 12)
                                          + ((hbase + (mt << 4) + c) << 5) + (q << 3));
            bf16x8 bfr[2];
            #pragma unroll
            for (int nt = 0; nt < 2; ++nt) {
                const int r = 16 * nt + c;           // r & 7 == c & 7
                const unsigned byte = (((unsigned)r << 9) + ((unsigned)kl << 6)
                                       + ((unsigned)q << 4))
                                      ^ (((unsigned)(c & 7)) << 4);
                bfr[nt] = *(const bf16x8*)(osb + byte);
            }
            #pragma unroll
            for (int mt = 0; mt < 2; ++mt)
                #pragma unroll
                for (int nt = 0; nt < 2; ++nt)
                    acc[mt][nt] = __builtin_amdgcn_mfma_f32_16x16x32_bf16(
                        af[mt], bfr[nt], acc[mt][nt], 0, 0, 0);
        }
        if (half == 0) __syncthreads();     // os + carr consumed before overwrite
    }

    #pragma unroll
    for (int mt = 0; mt < 2; ++mt) {
        const int h4 = hbase + 16 * mt + 4 * q;
        const float4 dd = *(const float4*)(Dv + h4);
        #pragma unroll
        for (int nt = 0; nt < 2; ++nt) {
            const int l = lbase + 16 * nt + c;
            const size_t off = ((size_t)l * NB + b) * NH + h4;
            const float4 uu = *(const float4*)(u + off);
            float4 ov;
            ov.x = acc[mt][nt][0] + dd.x * uu.x;
            ov.y = acc[mt][nt][1] + dd.y * uu.y;
            ov.z = acc[mt][nt][2] + dd.z * uu.z;
            ov.w = acc[mt][nt][3] + dd.w * uu.w;
            *(float4*)(out + off) = ov;
        }
    }
}

extern "C" void kernel_launch(void* const* d_in, const int* in_sizes, int n_in,
                              void* d_out, int out_size, void* d_ws, size_t ws_size,
                              hipStream_t stream)
{
    const float* u     = (const float*)d_in[0];
    const float* logLr = (const float*)d_in[1];
    const float* Lim   = (const float*)d_in[2];
    const float* Btr   = (const float*)d_in[3];
    const float* Bti   = (const float*)d_in[4];
    const float* Ctr   = (const float*)d_in[5];
    const float* Cti   = (const float*)d_in[6];
    const float* Dv    = (const float*)d_in[7];
    const float* logDt = (const float*)d_in[8];
    float* out = (float*)d_out;

    char* ws = (char*)d_ws;
    unsigned short* bu   = (unsigned short*)ws;                  // 67,108,864 B
    float2*         part = (float2*)(ws + 67108864);             //  4,194,304 B (carries -> entries in place)
    unsigned short* Bhat = (unsigned short*)(ws + 71303168);     //    131,072 B (BhatF)
    unsigned short* Chat = (unsigned short*)(ws + 71434240);     //    131,072 B (ChatF)

    k0<<<dim3((NP * NH) / 256), 256, 0, stream>>>(logLr, Lim, logDt,
                                                  Btr, Bti, Ctr, Cti, Bhat, Chat);
    gA<<<dim3(SL / 32, 2, NB), 256, 0, stream>>>(u, Bhat, logLr, Lim, logDt, bu, part);
    s2<<<dim3(NB), 256, 0, stream>>>(part, logLr, Lim, logDt);
    gB<<<dim3(SL / 32, NB), 256, 0, stream>>>((const unsigned*)bu, Chat, logLr, Lim,
                                              logDt, part, Dv, u, out);
}

// Round 8
// 168.370 us; speedup vs baseline: 1.3612x; 1.0501x over previous
//
#include <hip/hip_runtime.h>
#include <math.h>

#define SL 2048   // sequence length L
#define NB 32     // batch
#define NH 128    // feature dim H
#define NP 256    // state dim P (complex)
#define NP2 512   // interleaved real/imag columns

typedef short bf16x8 __attribute__((ext_vector_type(8)));
typedef float f32x4  __attribute__((ext_vector_type(4)));

static __device__ __forceinline__ unsigned short f2bf(float x) {
    unsigned u = __float_as_uint(x);
    return (unsigned short)((u + 0x7fffu + ((u >> 16) & 1u)) >> 16);  // RNE
}
static __device__ __forceinline__ float bf2f(unsigned short h) {
    return __uint_as_float(((unsigned)h) << 16);
}
static __device__ __forceinline__ void discretize(
    const float* __restrict__ logLr, const float* __restrict__ Lim,
    const float* __restrict__ logDt, int p, float& wr, float& wi)
{
    const float Lr = expf(logLr[p]);
    const float dt = expf(logDt[p]);
    const float ew = expf(-Lr * dt);
    const float ang = Lim[p] * dt;
    wr = ew * cosf(ang); wi = ew * sinf(ang);
}

// ---------------------------------------------------------------------------
// k0: pack BhatF, fragment-major f_p*B_tilde: BhatF[(h>>5)<<14 | p'<<5 | h&31]
// (coalesced 1 KB af loads) and ChatF[kk<<12 | h<<5 | col&31] (gF's GEMM2 af).
// ---------------------------------------------------------------------------
__global__ __launch_bounds__(256) void k0(
    const float* __restrict__ logLr, const float* __restrict__ Lim,
    const float* __restrict__ logDt,
    const float* __restrict__ Br, const float* __restrict__ Bi,
    const float* __restrict__ Cr, const float* __restrict__ Ci,
    unsigned short* __restrict__ BhatF, unsigned short* __restrict__ ChatF)
{
    const int tid = blockIdx.x * 256 + threadIdx.x;  // 32768 = P*H
    const int p = tid >> 7, h = tid & 127;
    float wr, wi; discretize(logLr, Lim, logDt, p, wr, wi);
    const float Lr = expf(logLr[p]), li = Lim[p];
    const float nr = wr - 1.0f, ni = wi;
    const float den = Lr * Lr + li * li;
    const float fr = (-nr * Lr + ni * li) / den;
    const float fi = (-ni * Lr - nr * li) / den;
    const float br = Br[p * NH + h], bi = Bi[p * NH + h];
    BhatF[((size_t)(h >> 5) << 14) + ((2 * p)     << 5) + (h & 31)] = f2bf(fr * br - fi * bi);
    BhatF[((size_t)(h >> 5) << 14) + ((2 * p + 1) << 5) + (h & 31)] = f2bf(fr * bi + fi * br);
    const int col0 = 2 * p, col1 = 2 * p + 1;
    ChatF[((size_t)(col0 >> 5) << 12) + (h << 5) + (col0 & 31)] = f2bf(Cr[h * NP + p]);
    ChatF[((size_t)(col1 >> 5) << 12) + (h << 5) + (col1 & 31)] = f2bf(-Ci[h * NP + p]);
}

// ---------------------------------------------------------------------------
// gA (carry-only): ONE independent 32-l x 256-p' tile per block (64 x 2 x 32
// grid). r7 structure minus the 64 MB bu store — GEMM1 output lives only in
// xs for the carry scan; gF recomputes it later (MFMA is ~3 us chip-wide).
// Writes just part (2 MB). (256,4): the only proven-spill-free bound.
// ---------------------------------------------------------------------------
__global__ __launch_bounds__(256, 4) void gA(
    const float* __restrict__ u, const unsigned short* __restrict__ BhatF,
    const float* __restrict__ logLr, const float* __restrict__ Lim,
    const float* __restrict__ logDt, float2* __restrict__ part)
{
    __shared__ unsigned short us[32][136];   // u tile bf16 [l][h], pad 8 (8704 B)
    __shared__ unsigned xs[32 * 129];        // out tile [l][128 complex], pitch 129

    const int m  = blockIdx.x;               // 32-l chunk, 0..63
    const int ph = blockIdx.y;               // p-half, 0..1
    const int b  = blockIdx.z;
    const int tid = threadIdx.x;
    const int w = tid >> 6, lane = tid & 63;
    const int q = lane >> 4, c = lane & 15;
    const int pbase = ph * 256 + w * 64;     // wave's 64 p' (global)
    const int l0 = m * 32;

    {   // stage u tile (32 l x 128 h) fp32 -> bf16 LDS
        const int lrow = tid >> 3;
        const int hcol = (tid & 7) * 16;
        const float* up = u + (size_t)(l0 + lrow) * (NB * NH) + b * NH + hcol;
        float4 a = *(const float4*)(up + 0);
        float4 d = *(const float4*)(up + 4);
        float4 e = *(const float4*)(up + 8);
        float4 g = *(const float4*)(up + 12);
        uint4 w0, w1;
        w0.x = (unsigned)f2bf(a.x) | ((unsigned)f2bf(a.y) << 16);
        w0.y = (unsigned)f2bf(a.z) | ((unsigned)f2bf(a.w) << 16);
        w0.z = (unsigned)f2bf(d.x) | ((unsigned)f2bf(d.y) << 16);
        w0.w = (unsigned)f2bf(d.z) | ((unsigned)f2bf(d.w) << 16);
        w1.x = (unsigned)f2bf(e.x) | ((unsigned)f2bf(e.y) << 16);
        w1.y = (unsigned)f2bf(e.z) | ((unsigned)f2bf(e.w) << 16);
        w1.z = (unsigned)f2bf(g.x) | ((unsigned)f2bf(g.y) << 16);
        w1.w = (unsigned)f2bf(g.z) | ((unsigned)f2bf(g.w) << 16);
        *(uint4*)&us[lrow][hcol + 0] = w0;
        *(uint4*)&us[lrow][hcol + 8] = w1;
    }
    __syncthreads();   // us ready

    f32x4 acc[4][2];
    #pragma unroll
    for (int mt = 0; mt < 4; ++mt)
        #pragma unroll
        for (int nt = 0; nt < 2; ++nt) acc[mt][nt] = (f32x4){0.f, 0.f, 0.f, 0.f};

    #pragma unroll
    for (int kk = 0; kk < 4; ++kk) {
        bf16x8 af[4];
        #pragma unroll
        for (int mt = 0; mt < 4; ++mt)
            af[mt] = *(const bf16x8*)(BhatF + ((size_t)kk << 14)
                                      + ((pbase + 16 * mt + c) << 5) + 8 * q);
        bf16x8 bfr[2];
        #pragma unroll
        for (int nt = 0; nt < 2; ++nt)
            bfr[nt] = *(const bf16x8*)&us[16 * nt + c][kk * 32 + 8 * q];
        #pragma unroll
        for (int mt = 0; mt < 4; ++mt)
            #pragma unroll
            for (int nt = 0; nt < 2; ++nt)
                acc[mt][nt] = __builtin_amdgcn_mfma_f32_16x16x32_bf16(
                    af[mt], bfr[nt], acc[mt][nt], 0, 0, 0);
    }

    // stash xs (bf16 pack — identical rounding to the old bu store)
    #pragma unroll
    for (int mt = 0; mt < 4; ++mt)
        #pragma unroll
        for (int nt = 0; nt < 2; ++nt) {
            const int rw  = 16 * nt + c;              // local l row
            const int ppl = w * 64 + 16 * mt + 4 * q; // local p' (0..255)
            ushort4 st;
            st.x = f2bf(acc[mt][nt][0]); st.y = f2bf(acc[mt][nt][1]);
            st.z = f2bf(acc[mt][nt][2]); st.w = f2bf(acc[mt][nt][3]);
            const int col = (ppl >> 1);               // local complex index 0..127
            xs[rw * 129 + col]     = (unsigned)st.x | ((unsigned)st.y << 16);
            xs[rw * 129 + col + 1] = (unsigned)st.z | ((unsigned)st.w << 16);
        }
    __syncthreads();   // xs ready

    // carry-only scan over 32 rows; threads 0..127 own this half's complex cols
    if (tid < 128) {
        float wr, wi; discretize(logLr, Lim, logDt, ph * 128 + tid, wr, wi);
        float sr = 0.f, si = 0.f;
        unsigned va[8], vb[8];
        #pragma unroll
        for (int j = 0; j < 8; ++j) va[j] = xs[j * 129 + tid];
        #pragma unroll
        for (int k8 = 0; k8 < 4; ++k8) {
            if (k8 < 3) {
                #pragma unroll
                for (int j = 0; j < 8; ++j) vb[j] = xs[((k8 + 1) * 8 + j) * 129 + tid];
            }
            #pragma unroll
            for (int j = 0; j < 8; ++j) {
                const float xr = bf2f((unsigned short)(va[j] & 0xffffu));
                const float xi = bf2f((unsigned short)(va[j] >> 16));
                const float tr = wr * sr - wi * si + xr;
                const float ti = wr * si + wi * sr + xi;
                sr = tr; si = ti;
            }
            #pragma unroll
            for (int j = 0; j < 8; ++j) va[j] = vb[j];
        }
        part[((size_t)b * 64 + m) * NP + ph * 128 + tid] = make_float2(sr, si);
    }
}

// ---------------------------------------------------------------------------
// s2: in-place scan of 32-l tile carries -> state ENTERING each tile,
// composed with W32 = w^32, 8-deep prefetch (r6-proven).
// ---------------------------------------------------------------------------
__global__ __launch_bounds__(256) void s2(
    float2* __restrict__ part, const float* __restrict__ logLr,
    const float* __restrict__ Lim, const float* __restrict__ logDt)
{
    const int b = blockIdx.x, p = threadIdx.x;
    float wr, wi; discretize(logLr, Lim, logDt, p, wr, wi);
    float Wr = wr, Wi = wi;
    #pragma unroll
    for (int t = 0; t < 5; ++t) { const float r = Wr * Wr - Wi * Wi; Wi = 2.f * Wr * Wi; Wr = r; }  // w^32
    const size_t base = (size_t)b * 64 * NP + p;
    float sr = 0.f, si = 0.f;
    float2 va[8], vb[8];
    #pragma unroll
    for (int j = 0; j < 8; ++j) va[j] = part[base + (size_t)j * NP];
    #pragma unroll
    for (int k8 = 0; k8 < 8; ++k8) {
        if (k8 < 7) {
            #pragma unroll
            for (int j = 0; j < 8; ++j)
                vb[j] = part[base + (size_t)((k8 + 1) * 8 + j) * NP];
        }
        #pragma unroll
        for (int j = 0; j < 8; ++j) {
            part[base + (size_t)(k8 * 8 + j) * NP] = make_float2(sr, si);  // entry
            const float tr = Wr * sr - Wi * si + va[j].x;
            const float ti = Wr * si + Wi * sr + va[j].y;
            sr = tr; si = ti;
        }
        #pragma unroll
        for (int j = 0; j < 8; ++j) va[j] = vb[j];
    }
}

// ---------------------------------------------------------------------------
// gF: fused GEMM1-recompute + replay + GEMM2 per (b, 32-l chunk). No bu in
// HBM at all: acc recompute is bitwise-identical to gA's (same fragments,
// same MFMA order), bf16 pack identical -> same values the carries came from.
// Per half: GEMM1 -> stash to swizzled osb (r7-gB layout: byte(row,col) =
// (row<<9) + ((col<<2) ^ ((row&7)<<4))) -> batch-load replay from entry in
// place -> GEMM2 half-K accumulate (r7-gB code). LDS 24.6 KB -> 6 blocks/CU.
// ---------------------------------------------------------------------------
__global__ __launch_bounds__(256, 4) void gF(
    const float* __restrict__ u, const unsigned short* __restrict__ BhatF,
    const unsigned short* __restrict__ ChatF,
    const float* __restrict__ logLr, const float* __restrict__ Lim,
    const float* __restrict__ logDt, const float2* __restrict__ Ent,
    const float* __restrict__ Dv, float* __restrict__ out)
{
    __shared__ unsigned short us[32][136];   // u tile bf16 (8704 B)
    __shared__ char osb[16384];              // o half-tile [32 l][128 complex], swizzled

    const int m = blockIdx.x, b = blockIdx.y;   // m: 32-l chunk, 0..63
    const int tid = threadIdx.x;
    const int w = tid >> 6, lane = tid & 63;
    const int q = lane >> 4, c = lane & 15;
    const int hbase = w * 32;              // GEMM2: wave owns a 32-h quadrant
    const int l0 = m * 32;

    {   // stage u tile (shared by both halves' GEMM1)
        const int lrow = tid >> 3;
        const int hcol = (tid & 7) * 16;
        const float* up = u + (size_t)(l0 + lrow) * (NB * NH) + b * NH + hcol;
        float4 a = *(const float4*)(up + 0);
        float4 d = *(const float4*)(up + 4);
        float4 e = *(const float4*)(up + 8);
        float4 g = *(const float4*)(up + 12);
        uint4 w0, w1;
        w0.x = (unsigned)f2bf(a.x) | ((unsigned)f2bf(a.y) << 16);
        w0.y = (unsigned)f2bf(a.z) | ((unsigned)f2bf(a.w) << 16);
        w0.z = (unsigned)f2bf(d.x) | ((unsigned)f2bf(d.y) << 16);
        w0.w = (unsigned)f2bf(d.z) | ((unsigned)f2bf(d.w) << 16);
        w1.x = (unsigned)f2bf(e.x) | ((unsigned)f2bf(e.y) << 16);
        w1.y = (unsigned)f2bf(e.z) | ((unsigned)f2bf(e.w) << 16);
        w1.z = (unsigned)f2bf(g.x) | ((unsigned)f2bf(g.y) << 16);
        w1.w = (unsigned)f2bf(g.z) | ((unsigned)f2bf(g.w) << 16);
        *(uint4*)&us[lrow][hcol + 0] = w0;
        *(uint4*)&us[lrow][hcol + 8] = w1;
    }
    __syncthreads();   // us ready

    f32x4 acc2[2][2];
    #pragma unroll
    for (int mt = 0; mt < 2; ++mt)
        #pragma unroll
        for (int nt = 0; nt < 2; ++nt) acc2[mt][nt] = (f32x4){0.f, 0.f, 0.f, 0.f};

    #pragma unroll 1
    for (int half = 0; half < 2; ++half) {
        // ---- GEMM1 recompute for this half (identical to gA) ----
        const int pbase = half * 256 + w * 64;
        f32x4 acc[4][2];
        #pragma unroll
        for (int mt = 0; mt < 4; ++mt)
            #pragma unroll
            for (int nt = 0; nt < 2; ++nt) acc[mt][nt] = (f32x4){0.f, 0.f, 0.f, 0.f};
        #pragma unroll
        for (int kk = 0; kk < 4; ++kk) {
            bf16x8 af[4];
            #pragma unroll
            for (int mt = 0; mt < 4; ++mt)
                af[mt] = *(const bf16x8*)(BhatF + ((size_t)kk << 14)
                                          + ((pbase + 16 * mt + c) << 5) + 8 * q);
            bf16x8 bfr[2];
            #pragma unroll
            for (int nt = 0; nt < 2; ++nt)
                bfr[nt] = *(const bf16x8*)&us[16 * nt + c][kk * 32 + 8 * q];
            #pragma unroll
            for (int mt = 0; mt < 4; ++mt)
                #pragma unroll
                for (int nt = 0; nt < 2; ++nt)
                    acc[mt][nt] = __builtin_amdgcn_mfma_f32_16x16x32_bf16(
                        af[mt], bfr[nt], acc[mt][nt], 0, 0, 0);
        }

        // ---- stash bf16 Bu into swizzled osb ----
        #pragma unroll
        for (int mt = 0; mt < 4; ++mt)
            #pragma unroll
            for (int nt = 0; nt < 2; ++nt) {
                const int row  = 16 * nt + c;
                const int col2 = w * 32 + 8 * mt + 2 * q;   // complex col, even
                ushort4 st;
                st.x = f2bf(acc[mt][nt][0]); st.y = f2bf(acc[mt][nt][1]);
                st.z = f2bf(acc[mt][nt][2]); st.w = f2bf(acc[mt][nt][3]);
                const unsigned byte = (((unsigned)row << 9)
                                       + (((unsigned)col2 << 2)
                                          ^ (((unsigned)(row & 7)) << 4)));
                uint2 st2 = { (unsigned)st.x | ((unsigned)st.y << 16),
                              (unsigned)st.z | ((unsigned)st.w << 16) };
                *(uint2*)(osb + byte) = st2;
            }
        __syncthreads();   // osb Bu ready

        // ---- replay in place from entry (threads 0..127, batch-loaded) ----
        if (tid < 128) {
            const int p = half * 128 + tid;
            float wr, wi; discretize(logLr, Lim, logDt, p, wr, wi);
            const float2 E = Ent[((size_t)(b * 64 + m)) * NP + p];
            float sr = E.x, si = E.y;
            unsigned va[32];
            #pragma unroll
            for (int j = 0; j < 32; ++j) {
                const unsigned byte = (((unsigned)j << 9)
                                       + (((unsigned)tid << 2)
                                          ^ (((unsigned)(j & 7)) << 4)));
                va[j] = *(const unsigned*)(osb + byte);
            }
            #pragma unroll
            for (int j = 0; j < 32; ++j) {
                const float xr = bf2f((unsigned short)(va[j] & 0xffffu));
                const float xi = bf2f((unsigned short)(va[j] >> 16));
                const float tr = wr * sr - wi * si + xr;
                const float ti = wr * si + wi * sr + xi;
                sr = tr; si = ti;
                va[j] = (unsigned)f2bf(tr) | ((unsigned)f2bf(ti) << 16);
            }
            #pragma unroll
            for (int j = 0; j < 32; ++j) {
                const unsigned byte = (((unsigned)j << 9)
                                       + (((unsigned)tid << 2)
                                          ^ (((unsigned)(j & 7)) << 4)));
                *(unsigned*)(osb + byte) = va[j];
            }
        }
        __syncthreads();   // replayed o ready

        // ---- GEMM2 this half's 8 kk (r7-gB code; acc2 persists) ----
        #pragma unroll 4
        for (int kl = 0; kl < 8; ++kl) {
            const int kk = half * 8 + kl;
            bf16x8 af2[2];
            #pragma unroll
            for (int mt = 0; mt < 2; ++mt)
                af2[mt] = *(const bf16x8*)(ChatF + ((size_t)kk << 12)
                                           + ((hbase + (mt << 4) + c) << 5) + (q << 3));
            bf16x8 bfr2[2];
            #pragma unroll
            for (int nt = 0; nt < 2; ++nt) {
                const int r = 16 * nt + c;
                const unsigned byte = ((((unsigned)r << 9) + ((unsigned)kl << 6)
                                        + ((unsigned)q << 4))
                                       ^ (((unsigned)(c & 7)) << 4));
                bfr2[nt] = *(const bf16x8*)(osb + byte);
            }
            #pragma unroll
            for (int mt = 0; mt < 2; ++mt)
                #pragma unroll
                for (int nt = 0; nt < 2; ++nt)
                    acc2[mt][nt] = __builtin_amdgcn_mfma_f32_16x16x32_bf16(
                        af2[mt], bfr2[nt], acc2[mt][nt], 0, 0, 0);
        }
        if (half == 0) __syncthreads();     // osb consumed before overwrite
    }

    // ---- epilogue: D-term + out (r7-gB verbatim) ----
    #pragma unroll
    for (int mt = 0; mt < 2; ++mt) {
        const int h4 = hbase + 16 * mt + 4 * q;
        const float4 dd = *(const float4*)(Dv + h4);
        #pragma unroll
        for (int nt = 0; nt < 2; ++nt) {
            const int l = l0 + 16 * nt + c;
            const size_t off = ((size_t)l * NB + b) * NH + h4;
            const float4 uu = *(const float4*)(u + off);
            float4 ov;
            ov.x = acc2[mt][nt][0] + dd.x * uu.x;
            ov.y = acc2[mt][nt][1] + dd.y * uu.y;
            ov.z = acc2[mt][nt][2] + dd.z * uu.z;
            ov.w = acc2[mt][nt][3] + dd.w * uu.w;
            *(float4*)(out + off) = ov;
        }
    }
}

extern "C" void kernel_launch(void* const* d_in, const int* in_sizes, int n_in,
                              void* d_out, int out_size, void* d_ws, size_t ws_size,
                              hipStream_t stream)
{
    const float* u     = (const float*)d_in[0];
    const float* logLr = (const float*)d_in[1];
    const float* Lim   = (const float*)d_in[2];
    const float* Btr   = (const float*)d_in[3];
    const float* Bti   = (const float*)d_in[4];
    const float* Ctr   = (const float*)d_in[5];
    const float* Cti   = (const float*)d_in[6];
    const float* Dv    = (const float*)d_in[7];
    const float* logDt = (const float*)d_in[8];
    float* out = (float*)d_out;

    char* ws = (char*)d_ws;
    float2*         part = (float2*)ws;                          //  4,194,304 B (carries -> entries in place)
    unsigned short* Bhat = (unsigned short*)(ws + 4194304);      //    131,072 B (BhatF)
    unsigned short* Chat = (unsigned short*)(ws + 4325376);      //    131,072 B (ChatF)

    k0<<<dim3((NP * NH) / 256), 256, 0, stream>>>(logLr, Lim, logDt,
                                                  Btr, Bti, Ctr, Cti, Bhat, Chat);
    gA<<<dim3(SL / 32, 2, NB), 256, 0, stream>>>(u, Bhat, logLr, Lim, logDt, part);
    s2<<<dim3(NB), 256, 0, stream>>>(part, logLr, Lim, logDt);
    gF<<<dim3(SL / 32, NB), 256, 0, stream>>>(u, Bhat, Chat, logLr, Lim, logDt,
                                              part, Dv, out);
}